// Round 4
// baseline (460.735 us; speedup 1.0000x reference)
//
#include <hip/hip_runtime.h>
#include <math.h>

#define N_    16
#define CIN_  16
#define T_    512
#define V_    200
#define K_    3
#define COUT_ 64
#define H_    64
#define G_    256  // 4*H

// Workspace layout (float offsets):
//   a  : [0, 600)                 a[k][v] = sum_w A[k,v,w] / V
//   sa : [640, 643)               sa[k] = sum_v a[k][v]
//   xa : [1024, 1024+16*512*48)   xa[n][t][k*16+ci]
//   xW : [WS_XW, +512*16*256)     xW[t][n][g]  (gate pre-activations from input side)
#define WS_A  0
#define WS_SA 640
#define WS_XA 1024
#define WS_XW (WS_XA + N_ * T_ * K_ * CIN_)

// fast activations: v_exp_f32-based, ~1e-6 rel err, saturate correctly
__device__ __forceinline__ float fast_sig(float x) {
    return __builtin_amdgcn_rcpf(1.f + __expf(-x));
}
__device__ __forceinline__ float fast_tanh(float x) {
    // 1 - 2/(1+e^{2x}); x->+inf: rcp(inf)=0 -> 1; x->-inf: 1-2*rcp(1) = -1
    return fmaf(-2.f, __builtin_amdgcn_rcpf(1.f + __expf(2.f * x)), 1.f);
}

// ---------------------------------------------------------------------------
// Kernel 1: copy A -> out[16:], compute a[k][v]
__global__ __launch_bounds__(256) void prep_kernel(const float* __restrict__ A,
                                                   float* __restrict__ out,
                                                   float* __restrict__ ws) {
    int tid = blockIdx.x * blockDim.x + threadIdx.x;
    if (tid < K_ * V_ * V_) out[16 + tid] = A[tid];
    if (tid < K_ * V_) {
        const float* row = A + (long)tid * V_;
        float s = 0.f;
        for (int w = 0; w < V_; ++w) s += row[w];
        ws[WS_A + tid] = s * (1.0f / V_);
    }
}

// Kernel 2: sa[k] = sum_v a[k][v]
__global__ void sa_kernel(float* __restrict__ ws) {
    int k = threadIdx.x;
    if (k < K_) {
        float s = 0.f;
        for (int v = 0; v < V_; ++v) s += ws[WS_A + k * V_ + v];
        ws[WS_SA + k] = s;
    }
}

// ---------------------------------------------------------------------------
// Kernel 3: xa[n][t][k*16+ci] = sum_v x[n][ci][t][v] * a[k][v]
// One wave per (n,ci,t) row; lanes stride over v (coalesced).
__global__ __launch_bounds__(256) void xa_kernel(const float* __restrict__ x,
                                                 float* __restrict__ ws) {
    __shared__ float aS[K_ * V_];
    int tid = threadIdx.x;
    for (int i = tid; i < K_ * V_; i += 256) aS[i] = ws[WS_A + i];
    __syncthreads();

    int wave = tid >> 6, lane = tid & 63;
    int row = blockIdx.x * 4 + wave;          // row = (n*CIN + ci)*T + t
    const float* xr = x + (long)row * V_;

    float s0 = 0.f, s1 = 0.f, s2 = 0.f;
    for (int v = lane; v < V_; v += 64) {
        float xv = xr[v];
        s0 = fmaf(xv, aS[v], s0);
        s1 = fmaf(xv, aS[V_ + v], s1);
        s2 = fmaf(xv, aS[2 * V_ + v], s2);
    }
    #pragma unroll
    for (int m = 1; m < 64; m <<= 1) {
        s0 += __shfl_xor(s0, m);
        s1 += __shfl_xor(s1, m);
        s2 += __shfl_xor(s2, m);
    }
    if (lane == 0) {
        int t  = row % T_;
        int nc = row / T_;
        int ci = nc % CIN_;
        int n  = nc / CIN_;
        long base = (long)(n * T_ + t) * (K_ * CIN_);
        ws[WS_XA + base + 0 * CIN_ + ci] = s0;
        ws[WS_XA + base + 1 * CIN_ + ci] = s1;
        ws[WS_XA + base + 2 * CIN_ + ci] = s2;
    }
}

// ---------------------------------------------------------------------------
// Kernel 4 (fused): seq[t][n][c] = sum_{k,ci} W_gcn[k*64+c][ci]*xa[n][t][k*16+ci]
//                                + sum_k b_gcn[k*64+c]*sa[k]
//                  xW[t][n][g]  = b_ih[g]+b_hh[g] + sum_c seq[c]*W_ih[g][c]
// One block per (n,t) pair.
__global__ __launch_bounds__(256) void gates_pre_kernel(
    const float* __restrict__ W_gcn, const float* __restrict__ b_gcn,
    const float* __restrict__ W_ih, const float* __restrict__ b_ih,
    const float* __restrict__ b_hh, float* __restrict__ ws) {
    int nt = blockIdx.x;
    int t = nt % T_, n = nt / T_;
    __shared__ float xaS[K_ * CIN_];
    __shared__ float seqS[COUT_];
    int tid = threadIdx.x;
    if (tid < K_ * CIN_)
        xaS[tid] = ws[WS_XA + (long)(n * T_ + t) * (K_ * CIN_) + tid];
    __syncthreads();
    if (tid < COUT_) {
        float s = 0.f;
        #pragma unroll
        for (int k = 0; k < K_; ++k) {
            s = fmaf(b_gcn[k * COUT_ + tid], ws[WS_SA + k], s);
            const float* wrow = W_gcn + (long)(k * COUT_ + tid) * CIN_;
            #pragma unroll
            for (int ci = 0; ci < CIN_; ++ci)
                s = fmaf(wrow[ci], xaS[k * CIN_ + ci], s);
        }
        seqS[tid] = s;
    }
    __syncthreads();
    float g = b_ih[tid] + b_hh[tid];
    const float* wrow = W_ih + (long)tid * H_;
    #pragma unroll 8
    for (int c = 0; c < H_; ++c) g = fmaf(wrow[c], seqS[c], g);
    ws[WS_XW + (long)(t * N_ + n) * G_ + tid] = g;
}

// ---------------------------------------------------------------------------
// Kernel 5: sequential LSTM scan. One block per batch element; 4 waves,
// wave w = gate type (torch order i,f,g,o), lane = gate/h index.
//  * W_hh row held in 64 VGPRs, pinned via empty asm so the compiler cannot
//    sink the loads back into the loop (round-3 showed VGPR_Count=44 ->
//    per-step global reloads).
//  * ONE barrier per step: gates cross waves via double-buffered gbuf;
//    every wave redundantly computes the activations and keeps replicated
//    (ccell, h) state; h is rebroadcast through a PRIVATE per-wave hS copy
//    (same-wave LDS dependency needs no barrier; dbuf gbuf is race-free
//    because rewriting buffer p at step t+2 requires passing barrier t+1,
//    which every reader of p at step t has already passed).
__global__ __launch_bounds__(256, 1) void lstm_kernel(
    const float* __restrict__ W_hh, const float* __restrict__ W_fc,
    const float* __restrict__ b_fc, const float* __restrict__ ws,
    float* __restrict__ out) {
    int n = blockIdx.x;
    int w = threadIdx.x >> 6;     // gate type
    int lane = threadIdx.x & 63;  // gate index / h index

    // One-time load of this thread's W_hh row, pinned into VGPRs.
    float4 wv[16];
    const float4* wr = (const float4*)(W_hh + (long)(w * H_ + lane) * H_);
    #pragma unroll
    for (int i = 0; i < 16; ++i) wv[i] = wr[i];
    #pragma unroll
    for (int i = 0; i < 16; ++i)
        asm volatile("" : "+v"(wv[i].x), "+v"(wv[i].y), "+v"(wv[i].z), "+v"(wv[i].w));

    __shared__ __align__(16) float hS[4][H_];   // private h copy per wave
    __shared__ float gbuf[2][4][H_];            // double-buffered gate exchange

    hS[w][lane] = 0.f;
    float ccell = 0.f, h = 0.f;                 // replicated in every wave

    const float* xw = ws + WS_XW + (long)n * G_ + (w * H_ + lane);
    // depth-2 prefetch of the input-side gate pre-activations
    float x0 = xw[0];
    float x1 = xw[(long)N_ * G_];

    for (int t = 0; t < T_; ++t) {
        float gate = x0;
        x0 = x1;
        if (t + 2 < T_) x1 = xw[(long)(t + 2) * N_ * G_];

        // gate += dot(W row, h) — h broadcast from this wave's private hS
        // (uniform-address b128, conflict-free), 4 accumulators for ILP.
        float a0 = 0.f, a1 = 0.f, a2 = 0.f, a3 = 0.f;
        const float4* h4 = (const float4*)hS[w];
        #pragma unroll
        for (int i = 0; i < 16; ++i) {
            float4 hv = h4[i];
            a0 = fmaf(wv[i].x, hv.x, a0);
            a1 = fmaf(wv[i].y, hv.y, a1);
            a2 = fmaf(wv[i].z, hv.z, a2);
            a3 = fmaf(wv[i].w, hv.w, a3);
        }
        gate += (a0 + a1) + (a2 + a3);

        int p = t & 1;
        gbuf[p][w][lane] = gate;
        __syncthreads();               // the ONLY barrier per step
        float iv = fast_sig(gbuf[p][0][lane]);
        float fv = fast_sig(gbuf[p][1][lane]);
        float gv = fast_tanh(gbuf[p][2][lane]);
        float ov = fast_sig(gbuf[p][3][lane]);
        ccell = fmaf(fv, ccell, iv * gv);
        h = ov * fast_tanh(ccell);
        hS[w][lane] = h;               // same-wave write; lgkmcnt orders reads
    }

    // out[n] = dot(h, W_fc) + b_fc  (state replicated; wave 0 writes)
    if (w == 0) {
        float p = h * W_fc[lane];
        #pragma unroll
        for (int m = 1; m < 64; m <<= 1) p += __shfl_xor(p, m);
        if (lane == 0) out[n] = p + b_fc[0];
    }
}

// ---------------------------------------------------------------------------
extern "C" void kernel_launch(void* const* d_in, const int* in_sizes, int n_in,
                              void* d_out, int out_size, void* d_ws, size_t ws_size,
                              hipStream_t stream) {
    const float* x     = (const float*)d_in[0];
    const float* A     = (const float*)d_in[1];
    const float* W_gcn = (const float*)d_in[2];
    const float* b_gcn = (const float*)d_in[3];
    const float* W_ih  = (const float*)d_in[4];
    const float* W_hh  = (const float*)d_in[5];
    const float* b_ih  = (const float*)d_in[6];
    const float* b_hh  = (const float*)d_in[7];
    const float* W_fc  = (const float*)d_in[8];
    const float* b_fc  = (const float*)d_in[9];
    float* out = (float*)d_out;
    float* ws  = (float*)d_ws;

    // 1) copy A to out, compute a[k][v]
    int copy_elems = K_ * V_ * V_;
    prep_kernel<<<(copy_elems + 255) / 256, 256, 0, stream>>>(A, out, ws);
    // 2) sa[k]
    sa_kernel<<<1, 64, 0, stream>>>(ws);
    // 3) xa
    int rows = N_ * CIN_ * T_;             // 131072 rows, one wave each
    xa_kernel<<<rows / 4, 256, 0, stream>>>(x, ws);
    // 4) seq + input-side gate pre-activations
    gates_pre_kernel<<<N_ * T_, 256, 0, stream>>>(W_gcn, b_gcn, W_ih, b_ih, b_hh, ws);
    // 5) sequential LSTM scan + final FC
    lstm_kernel<<<N_, 256, 0, stream>>>(W_hh, W_fc, b_fc, ws, out);
}